// Round 6
// baseline (532.961 us; speedup 1.0000x reference)
//
#include <hip/hip_runtime.h>
#include <hip/hip_bf16.h>
#include <cstdint>
#include <cmath>

#define S_LEN 4096
#define DMODEL 2048
#define NH 16
#define NKV 4
#define HD 128
#define NQKV 3072  // 2048 Q + 512 K + 512 V

typedef unsigned short u16;
typedef unsigned int u32;
typedef __attribute__((ext_vector_type(8))) __bf16 bf16x8;
typedef __attribute__((ext_vector_type(4))) float f32x4;
typedef __attribute__((ext_vector_type(16))) float f32x16;
typedef __attribute__((ext_vector_type(4))) int i32x4;

__device__ __forceinline__ u16 f2bf(float f) {
  __bf16 h = (__bf16)f;  // RNE
  return __builtin_bit_cast(u16, h);
}
__device__ __forceinline__ float bf2f(u16 u) {
  return (float)__builtin_bit_cast(__bf16, u);
}
// pack two f32 -> u32 of two bf16 (lo=a, hi=b); scalar casts, compiler fuses
__device__ __forceinline__ u32 pk2(float a, float b) {
  return (u32)f2bf(a) | ((u32)f2bf(b) << 16);
}

__device__ __forceinline__ void gload16(const void* g, void* l) {
  __builtin_amdgcn_global_load_lds(
      (const __attribute__((address_space(1))) void*)g,
      (__attribute__((address_space(3))) void*)l, 16, 0, 0);
}

// ---------------- pack / convert ----------------
__global__ void k_f32_to_bf16(const float* __restrict__ src, u16* __restrict__ dst, int n4) {
  int i = blockIdx.x * blockDim.x + threadIdx.x;
  if (i < n4) {
    float4 v = reinterpret_cast<const float4*>(src)[i];
    ushort4 o = make_ushort4(f2bf(v.x), f2bf(v.y), f2bf(v.z), f2bf(v.w));
    reinterpret_cast<ushort4*>(dst)[i] = o;
  }
}

// dst[n][k] = bf16(src[k][n])
__global__ void k_transpose_f32_bf16(const float* __restrict__ src, int srcStride,
                                     u16* __restrict__ dst, int dstStride) {
  __shared__ float tile[32][33];
  int n0 = blockIdx.x * 32, k0 = blockIdx.y * 32;
  int tx = threadIdx.x, ty = threadIdx.y;  // 32 x 8
#pragma unroll
  for (int r = 0; r < 32; r += 8)
    tile[ty + r][tx] = src[(size_t)(k0 + ty + r) * srcStride + n0 + tx];
  __syncthreads();
#pragma unroll
  for (int r = 0; r < 32; r += 8)
    dst[(size_t)(n0 + ty + r) * dstStride + k0 + tx] = f2bf(tile[tx][ty + r]);
}

__global__ void k_transpose_bf16(const u16* __restrict__ src, int srcStride,
                                 u16* __restrict__ dst, int dstStride) {
  __shared__ u16 tile[32][33];
  int n0 = blockIdx.x * 32, k0 = blockIdx.y * 32;
  int tx = threadIdx.x, ty = threadIdx.y;  // 32 x 8
#pragma unroll
  for (int r = 0; r < 32; r += 8)
    tile[ty + r][tx] = src[(size_t)(k0 + ty + r) * srcStride + n0 + tx];
  __syncthreads();
#pragma unroll
  for (int r = 0; r < 32; r += 8)
    dst[(size_t)(n0 + ty + r) * dstStride + k0 + tx] = tile[tx][ty + r];
}

// ---------------- RoPE ----------------
// Q gets 1/sqrt(HD) * LOG2E folded in (softmax runs in exp2 domain).
__global__ void k_rope(const u16* __restrict__ qkv, const int* __restrict__ pos_ids,
                       u16* __restrict__ Qb, u16* __restrict__ Kb) {
  int s = blockIdx.x;
  float pos = (float)pos_ids[s];
  const u16* row = qkv + (size_t)s * NQKV;
  const float L2B = 13.287712379549449f;  // log2(10000)
  const float QSCALE = 0.08838834764831845f * 1.4426950408889634f;
  for (int c = threadIdx.x; c < DMODEL + NKV * HD; c += blockDim.x) {
    int d = c & 127;
    int dh = d & 63;
    float invf = exp2f(-(float)dh * (L2B / 64.0f));
    float ang = pos * invf;
    float cv = cosf(ang), sv = sinf(ang);
    float x = bf2f(row[c]);
    float xp = bf2f(row[c ^ 64]);
    float rot = (d < 64) ? -xp : xp;
    float out = x * cv + rot * sv;
    if (c < DMODEL) {
      int h = c >> 7;
      out *= QSCALE;
      Qb[((size_t)h * S_LEN + s) * HD + d] = f2bf(out);
    } else {
      int kvh = (c - DMODEL) >> 7;
      Kb[((size_t)kvh * S_LEN + s) * HD + d] = f2bf(out);
    }
  }
}

// ---------------- m97-style 128x128 GEMM, B^T operand ----------------
template <int OUT_BF16>
__global__ __launch_bounds__(256) void k_gemm_bt(const u16* __restrict__ A,
                                                 const u16* __restrict__ BT,
                                                 void* __restrict__ C, int M, int N, int K) {
  __shared__ __align__(16) u16 As[128 * 32];
  __shared__ __align__(16) u16 Bs[128 * 32];
  const int tid = threadIdx.x, wave = tid >> 6, lane = tid & 63;
  const int fr = lane & 15, fq = lane >> 4;
  const int rowBase = blockIdx.y * 128, colBase = blockIdx.x * 128;
  const int wr = wave >> 1, wc = wave & 1;
  f32x4 acc[4][4] = {};
  const int nk = K >> 5;
  for (int kt = 0; kt < nk; ++kt) {
    const int k0 = kt << 5;
#pragma unroll
    for (int p = 0; p < 2; ++p) {
      int cbase = p * 256 + wave * 64;
      int chunk = cbase + lane;
      int r = chunk >> 2, cb = chunk & 3;
      gload16(A + (size_t)(rowBase + r) * K + k0 + cb * 8, (char*)As + cbase * 16);
      gload16(BT + (size_t)(colBase + r) * K + k0 + cb * 8, (char*)Bs + cbase * 16);
    }
    __syncthreads();
    bf16x8 a[4], b[4];
#pragma unroll
    for (int m = 0; m < 4; ++m)
      a[m] = *reinterpret_cast<const bf16x8*>(&As[(wr * 64 + m * 16 + fr) * 32 + fq * 8]);
#pragma unroll
    for (int n = 0; n < 4; ++n)
      b[n] = *reinterpret_cast<const bf16x8*>(&Bs[(wc * 64 + n * 16 + fr) * 32 + fq * 8]);
#pragma unroll
    for (int m = 0; m < 4; ++m)
#pragma unroll
      for (int n = 0; n < 4; ++n)
        acc[m][n] = __builtin_amdgcn_mfma_f32_16x16x32_bf16(a[m], b[n], acc[m][n], 0, 0, 0);
    __syncthreads();
  }
#pragma unroll
  for (int m = 0; m < 4; ++m) {
    int row0 = rowBase + wr * 64 + m * 16 + fq * 4;
#pragma unroll
    for (int n = 0; n < 4; ++n) {
      int col = colBase + wc * 64 + n * 16 + fr;
#pragma unroll
      for (int j = 0; j < 4; ++j) {
        if (OUT_BF16)
          ((u16*)C)[(size_t)(row0 + j) * N + col] = f2bf(acc[m][n][j]);
        else
          ((float*)C)[(size_t)(row0 + j) * N + col] = acc[m][n][j];
      }
    }
  }
}

// ---------------- flash attention (causal, GQA) ----------------
// 8 waves, 512 thr. Waves split: group A (0-3) = k-cols 0..63 of each KT=128
// step, group B (4-7) = k-cols 64..127; both cover the same 128 q-rows
// (4 pairs x 32q, R5's swapped 32x32 MFMA + in-register softmax per wave).
// Independent online softmax per group; ONE flash-combine per q-tile through
// LDS. Serial q-tile pair {31-p, p}: every block exactly 33 steps ->
// 256 blocks = 1/CU, perfect balance, 8 waves/CU.
// Qb [H][S][HD] (pre-scaled by 1/sqrt(HD)*LOG2E), Kb [KV][S][HD],
// VT [KV][HD][S], AO [S][H*HD]
__device__ __forceinline__ void stage_kv128(const u16* __restrict__ Kbk,
                                            const u16* __restrict__ VTk, int kb,
                                            char* KsB, char* VsB, int tid) {
#pragma unroll
  for (int it = 0; it < 4; ++it) {
    int slot = it * 512 + tid;
    int r = slot >> 4, cb = slot & 15;
    int cbs = cb ^ (r & 15);  // pre-swizzled source -> linear LDS dest (G21)
    gload16(Kbk + (size_t)(kb + r) * HD + cbs * 8, KsB + slot * 16);
    gload16(VTk + (size_t)r * S_LEN + kb + cbs * 8, VsB + slot * 16);
  }
}

__global__ __launch_bounds__(512) void k_attn(const u16* __restrict__ Qb,
                                              const u16* __restrict__ Kb,
                                              const u16* __restrict__ VT,
                                              u16* __restrict__ AO) {
  __shared__ __align__(16) u16 Ks[2][128 * 128];  // [k][d], ^(k&15) chunk swz, 64KB
  __shared__ __align__(16) u16 Vs[2][128 * 128];  // [d][k], ^(d&15) chunk swz, 64KB
  const int h = blockIdx.x;
  const int p = blockIdx.y;  // 0..15
  const int kv = h >> 2;
  const int tid = threadIdx.x, wave = tid >> 6, lane = tid & 63;
  const int grp = wave >> 2, pr = wave & 3;  // k-group, q-pair
  const int ql = lane & 31, hi = lane >> 5;
  const float DEFER_THR = 11.541560327111707f;  // 8 * log2(e)

  const u16* Kbk = Kb + (size_t)kv * S_LEN * HD;
  const u16* VTk = VT + (size_t)kv * HD * S_LEN;

#pragma unroll 1
  for (int half = 0; half < 2; ++half) {
    const int qt = half ? p : (31 - p);
    const int qg0w = qt * 128 + pr * 32;  // wave's first q row
    const int qglob = qg0w + ql;          // this lane's q row

    __syncthreads();  // prior combine readers done before restaging Ks/Vs
    stage_kv128(Kbk, VTk, 0, (char*)Ks[0], (char*)Vs[0], tid);

    // Q as B-operand frags: lane(ql,hi) holds Q[qglob][t*16 + hi*8 + e]
    bf16x8 qf[8];
    {
      const u16* qp = Qb + ((size_t)h * S_LEN + qglob) * HD;
#pragma unroll
      for (int t = 0; t < 8; ++t)
        qf[t] = *reinterpret_cast<const bf16x8*>(qp + t * 16 + hi * 8);
    }
    f32x16 o[4] = {};  // O^T: lane(q=ql,hi) holds O[q][d0*32+(r&3)+8*(r>>2)+4*hi]
    float m = -INFINITY, l = 0.f;

    __syncthreads();  // tile 0 staged

    int buf = 0;
    const int nkt = qt + 1;
    for (int kt = 0; kt < nkt; ++kt) {
      if (kt + 1 < nkt)
        stage_kv128(Kbk, VTk, (kt + 1) * 128, (char*)Ks[buf ^ 1], (char*)Vs[buf ^ 1], tid);
      const int kbg = kt * 128 + grp * 64;  // this group's k base
      if (kbg <= qg0w + 31) {               // wave has >=1 unmasked column
        const char* Kc = (const char*)Ks[buf];
        const char* Vc = (const char*)Vs[buf];

        // S^T = mfma(A=K rows, B=Q): st0 = group k 0..31, st1 = 32..63
        f32x16 st0 = {}, st1 = {};
#pragma unroll
        for (int t = 0; t < 8; ++t) {
          int ch = (2 * t + hi) ^ (ql & 15);
          const int r0 = grp * 64 + ql, r1 = grp * 64 + 32 + ql;
          bf16x8 kf0 = *reinterpret_cast<const bf16x8*>(Kc + r0 * 256 + ch * 16);
          bf16x8 kf1 = *reinterpret_cast<const bf16x8*>(Kc + r1 * 256 + ch * 16);
          st0 = __builtin_amdgcn_mfma_f32_32x32x16_bf16(kf0, qf[t], st0, 0, 0, 0);
          st1 = __builtin_amdgcn_mfma_f32_32x32x16_bf16(kf1, qf[t], st1, 0, 0, 0);
        }
        // causal mask: lane reg r holds k_local = (r&3)+8*(r>>2)+4*hi
        if (kbg + 63 > qg0w) {
#pragma unroll
          for (int r = 0; r < 16; ++r) {
            int kl = (r & 3) + 8 * (r >> 2) + 4 * hi;
            if (kbg + kl > qglob) st0[r] = -1e30f;
            if (kbg + 32 + kl > qglob) st1[r] = -1e30f;
          }
        }
        // row max: in-lane tree over 32 values, then lane-pair combine (xor 32)
        float mx[16];
#pragma unroll
        for (int r = 0; r < 16; ++r) mx[r] = fmaxf(st0[r], st1[r]);
#pragma unroll
        for (int s = 8; s > 0; s >>= 1)
#pragma unroll
          for (int r = 0; r < 16; ++r)
            if (r < s) mx[r] = fmaxf(mx[r], mx[r + s]);
        float tmax = fmaxf(mx[0], __shfl_xor(mx[0], 32));
        // defer-max (T13)
        if (__any(tmax - m > DEFER_THR)) {
          float mn = fmaxf(m, tmax);
          float corr = exp2f(m - mn);
          m = mn;
          l *= corr;
#pragma unroll
          for (int d0 = 0; d0 < 4; ++d0) o[d0] *= corr;
        }
        // P = exp2(S - m); in-lane sum + lane-pair combine
        float sm[16];
#pragma unroll
        for (int r = 0; r < 16; ++r) {
          st0[r] = exp2f(st0[r] - m);
          st1[r] = exp2f(st1[r] - m);
          sm[r] = st0[r] + st1[r];
        }
#pragma unroll
        for (int s = 8; s > 0; s >>= 1)
#pragma unroll
          for (int r = 0; r < 16; ++r)
            if (r < s) sm[r] += sm[r + s];
        l += sm[0] + __shfl_xor(sm[0], 32);

        // P -> bf16 B-frags in-register (pack + shfl_xor(32) + select).
        // Frag slot (hi,e) holds P[q][kc*16 + hi*8 + e] (k local to group).
        bf16x8 pa[4];
#pragma unroll
        for (int kc = 0; kc < 4; ++kc) {
          int rb = 8 * (kc & 1);
          u32 w0, w1, w2, w3;
          if (kc < 2) {
            w0 = pk2(st0[rb + 0], st0[rb + 1]);
            w1 = pk2(st0[rb + 2], st0[rb + 3]);
            w2 = pk2(st0[rb + 4], st0[rb + 5]);
            w3 = pk2(st0[rb + 6], st0[rb + 7]);
          } else {
            w0 = pk2(st1[rb + 0], st1[rb + 1]);
            w1 = pk2(st1[rb + 2], st1[rb + 3]);
            w2 = pk2(st1[rb + 4], st1[rb + 5]);
            w3 = pk2(st1[rb + 6], st1[rb + 7]);
          }
          u32 xw0 = (u32)__shfl_xor((int)w0, 32);
          u32 xw1 = (u32)__shfl_xor((int)w1, 32);
          u32 xw2 = (u32)__shfl_xor((int)w2, 32);
          u32 xw3 = (u32)__shfl_xor((int)w3, 32);
          i32x4 pw;
          pw[0] = (int)(hi ? xw2 : w0);
          pw[1] = (int)(hi ? xw3 : w1);
          pw[2] = (int)(hi ? w2 : xw0);
          pw[3] = (int)(hi ? w3 : xw1);
          pa[kc] = __builtin_bit_cast(bf16x8, pw);
        }
        // O^T += mfma(A=V^T rows, B=P^T) over this group's 64 k-cols
#pragma unroll
        for (int d0 = 0; d0 < 4; ++d0) {
          int dr = d0 * 32 + ql;
#pragma unroll
          for (int kc = 0; kc < 4; ++kc) {
            int ch = (grp * 8 + 2 * kc + hi) ^ (ql & 15);
            bf16x8 vf = *reinterpret_cast<const bf16x8*>(Vc + dr * 256 + ch * 16);
            o[d0] = __builtin_amdgcn_mfma_f32_32x32x16_bf16(vf, pa[kc], o[d0], 0, 0, 0);
          }
        }
      }
      __syncthreads();  // next tile staged; buf safe to flip
      buf ^= 1;
    }

    // ---- flash-combine of the two k-groups (once per q-tile) ----
    // Group A merges+stores d0 {0,1}, writes o[2],o[3]; group B the reverse.
    const int mbase = grp ? 2 : 0;
    const int wbase = grp ? 0 : 2;
    float2* exch = (float2*)Ks;  // [d0 4][rp 8][pr 4][lane 64] float2 = 64KB
    float2* mlb = (float2*)Vs;   // [grp 2][pr 4][ql 32] float2
#pragma unroll
    for (int i = 0; i < 2; ++i)
#pragma unroll
      for (int rp = 0; rp < 8; ++rp) {
        int d0 = wbase + i;
        float2 v;
        v.x = o[d0][2 * rp];
        v.y = o[d0][2 * rp + 1];
        exch[((d0 * 8 + rp) * 4 + pr) * 64 + lane] = v;
      }
    if (hi == 0) {
      float2 v;
      v.x = m;
      v.y = l;
      mlb[(grp * 4 + pr) * 32 + ql] = v;
    }
    __syncthreads();
    {
      float2 pml = mlb[((1 - grp) * 4 + pr) * 32 + ql];
      float mm = fmaxf(m, pml.x);
      float fa = exp2f(m - mm), fb = exp2f(pml.x - mm);
      float ll = l * fa + pml.y * fb;
      float inv = 1.0f / ll;
      u16* aoRow = AO + (size_t)qglob * DMODEL + h * HD;
#pragma unroll
      for (int i = 0; i < 2; ++i)
#pragma unroll
        for (int rp = 0; rp < 8; ++rp) {
          int d0 = mbase + i;
          float2 po = exch[((d0 * 8 + rp) * 4 + pr) * 64 + lane];
          int r = 2 * rp;
          float u0 = (o[d0][r] * fa + po.x * fb) * inv;
          float u1 = (o[d0][r + 1] * fa + po.y * fb) * inv;
          int d = d0 * 32 + (r & 3) + 8 * (r >> 2) + 4 * hi;
          *reinterpret_cast<u32*>(aoRow + d) = pk2(u0, u1);
        }
    }
    // loop-top __syncthreads protects Ks/Vs before next tile's staging
  }
}

// ---------------- launch ----------------
extern "C" void kernel_launch(void* const* d_in, const int* in_sizes, int n_in,
                              void* d_out, int out_size, void* d_ws, size_t ws_size,
                              hipStream_t stream) {
  const float* hidden = (const float*)d_in[0];
  const float* Wq = (const float*)d_in[1];
  const float* Wk = (const float*)d_in[2];
  const float* Wv = (const float*)d_in[3];
  const float* Wo = (const float*)d_in[4];
  // d_in[5] = attention_mask: causal, applied analytically (unused)
  const int* pos_ids = (const int*)d_in[6];
  float* out = (float*)d_out;

  char* ws = (char*)d_ws;
  u16* Xb   = (u16*)(ws);                               // [4096][2048]   16MB
  u16* Wt   = (u16*)(ws + (16ull << 20));               // [3072][2048]   12MB
  u16* WoT  = (u16*)(ws + (28ull << 20));               // [2048][2048]    8MB
  u16* QKVb = (u16*)(ws + (36ull << 20));               // [4096][3072]   24MB
  u16* Qb   = (u16*)(ws + (60ull << 20));               // [16][4096][128] 16MB
  u16* Kb   = (u16*)(ws + (76ull << 20));               // [4][4096][128]   4MB
  u16* VT   = (u16*)(ws + (80ull << 20));               // [4][128][4096]   4MB
  u16* AO   = QKVb;  // alias: QKVb fully consumed before attention writes AO

  dim3 tb(32, 8);
  k_f32_to_bf16<<<dim3((S_LEN * DMODEL / 4) / 256), dim3(256), 0, stream>>>(
      hidden, Xb, S_LEN * DMODEL / 4);
  k_transpose_f32_bf16<<<dim3(64, 64), tb, 0, stream>>>(Wq, 2048, Wt, 2048);
  k_transpose_f32_bf16<<<dim3(16, 64), tb, 0, stream>>>(Wk, 512, Wt + (size_t)2048 * 2048, 2048);
  k_transpose_f32_bf16<<<dim3(16, 64), tb, 0, stream>>>(Wv, 512, Wt + (size_t)2560 * 2048, 2048);
  k_transpose_f32_bf16<<<dim3(64, 64), tb, 0, stream>>>(Wo, 2048, WoT, 2048);

  k_gemm_bt<1><<<dim3(24, 32), 256, 0, stream>>>(Xb, Wt, QKVb, S_LEN, NQKV, DMODEL);

  k_rope<<<dim3(S_LEN), 256, 0, stream>>>(QKVb, pos_ids, Qb, Kb);
  k_transpose_bf16<<<dim3(16, 128), tb, 0, stream>>>(QKVb + 2560, NQKV, VT, S_LEN);

  k_attn<<<dim3(NH, 16), 512, 0, stream>>>(Qb, Kb, VT, AO);

  k_gemm_bt<0><<<dim3(16, 32), 256, 0, stream>>>(AO, WoT, out, S_LEN, DMODEL, DMODEL);
}

// Round 7
// 532.550 us; speedup vs baseline: 1.0008x; 1.0008x over previous
//
#include <hip/hip_runtime.h>
#include <hip/hip_bf16.h>
#include <cstdint>
#include <cmath>

#define S_LEN 4096
#define DMODEL 2048
#define NH 16
#define NKV 4
#define HD 128
#define NQKV 3072  // 2048 Q + 512 K + 512 V

typedef unsigned short u16;
typedef unsigned int u32;
typedef __attribute__((ext_vector_type(8))) __bf16 bf16x8;
typedef __attribute__((ext_vector_type(4))) float f32x4;
typedef __attribute__((ext_vector_type(16))) float f32x16;
typedef __attribute__((ext_vector_type(4))) int i32x4;

__device__ __forceinline__ u16 f2bf(float f) {
  __bf16 h = (__bf16)f;  // RNE
  return __builtin_bit_cast(u16, h);
}
__device__ __forceinline__ float bf2f(u16 u) {
  return (float)__builtin_bit_cast(__bf16, u);
}
// pack two f32 -> u32 of two bf16 (lo=a, hi=b); scalar casts, compiler fuses
__device__ __forceinline__ u32 pk2(float a, float b) {
  return (u32)f2bf(a) | ((u32)f2bf(b) << 16);
}

__device__ __forceinline__ void gload16(const void* g, void* l) {
  __builtin_amdgcn_global_load_lds(
      (const __attribute__((address_space(1))) void*)g,
      (__attribute__((address_space(3))) void*)l, 16, 0, 0);
}

// ---------------- pack / convert ----------------
__global__ void k_f32_to_bf16(const float* __restrict__ src, u16* __restrict__ dst, int n4) {
  int i = blockIdx.x * blockDim.x + threadIdx.x;
  if (i < n4) {
    float4 v = reinterpret_cast<const float4*>(src)[i];
    ushort4 o = make_ushort4(f2bf(v.x), f2bf(v.y), f2bf(v.z), f2bf(v.w));
    reinterpret_cast<ushort4*>(dst)[i] = o;
  }
}

// dst[n][k] = bf16(src[k][n])
__global__ void k_transpose_f32_bf16(const float* __restrict__ src, int srcStride,
                                     u16* __restrict__ dst, int dstStride) {
  __shared__ float tile[32][33];
  int n0 = blockIdx.x * 32, k0 = blockIdx.y * 32;
  int tx = threadIdx.x, ty = threadIdx.y;  // 32 x 8
#pragma unroll
  for (int r = 0; r < 32; r += 8)
    tile[ty + r][tx] = src[(size_t)(k0 + ty + r) * srcStride + n0 + tx];
  __syncthreads();
#pragma unroll
  for (int r = 0; r < 32; r += 8)
    dst[(size_t)(n0 + ty + r) * dstStride + k0 + tx] = f2bf(tile[tx][ty + r]);
}

__global__ void k_transpose_bf16(const u16* __restrict__ src, int srcStride,
                                 u16* __restrict__ dst, int dstStride) {
  __shared__ u16 tile[32][33];
  int n0 = blockIdx.x * 32, k0 = blockIdx.y * 32;
  int tx = threadIdx.x, ty = threadIdx.y;  // 32 x 8
#pragma unroll
  for (int r = 0; r < 32; r += 8)
    tile[ty + r][tx] = src[(size_t)(k0 + ty + r) * srcStride + n0 + tx];
  __syncthreads();
#pragma unroll
  for (int r = 0; r < 32; r += 8)
    dst[(size_t)(n0 + ty + r) * dstStride + k0 + tx] = tile[tx][ty + r];
}

// ---------------- RoPE ----------------
// Q gets 1/sqrt(HD) * LOG2E folded in (softmax runs in exp2 domain).
__global__ void k_rope(const u16* __restrict__ qkv, const int* __restrict__ pos_ids,
                       u16* __restrict__ Qb, u16* __restrict__ Kb) {
  int s = blockIdx.x;
  float pos = (float)pos_ids[s];
  const u16* row = qkv + (size_t)s * NQKV;
  const float L2B = 13.287712379549449f;  // log2(10000)
  const float QSCALE = 0.08838834764831845f * 1.4426950408889634f;
  for (int c = threadIdx.x; c < DMODEL + NKV * HD; c += blockDim.x) {
    int d = c & 127;
    int dh = d & 63;
    float invf = exp2f(-(float)dh * (L2B / 64.0f));
    float ang = pos * invf;
    float cv = cosf(ang), sv = sinf(ang);
    float x = bf2f(row[c]);
    float xp = bf2f(row[c ^ 64]);
    float rot = (d < 64) ? -xp : xp;
    float out = x * cv + rot * sv;
    if (c < DMODEL) {
      int h = c >> 7;
      out *= QSCALE;
      Qb[((size_t)h * S_LEN + s) * HD + d] = f2bf(out);
    } else {
      int kvh = (c - DMODEL) >> 7;
      Kb[((size_t)kvh * S_LEN + s) * HD + d] = f2bf(out);
    }
  }
}

// ---------------- m97-style 128x128 GEMM, B^T operand ----------------
template <int OUT_BF16>
__global__ __launch_bounds__(256) void k_gemm_bt(const u16* __restrict__ A,
                                                 const u16* __restrict__ BT,
                                                 void* __restrict__ C, int M, int N, int K) {
  __shared__ __align__(16) u16 As[128 * 32];
  __shared__ __align__(16) u16 Bs[128 * 32];
  const int tid = threadIdx.x, wave = tid >> 6, lane = tid & 63;
  const int fr = lane & 15, fq = lane >> 4;
  const int rowBase = blockIdx.y * 128, colBase = blockIdx.x * 128;
  const int wr = wave >> 1, wc = wave & 1;
  f32x4 acc[4][4] = {};
  const int nk = K >> 5;
  for (int kt = 0; kt < nk; ++kt) {
    const int k0 = kt << 5;
#pragma unroll
    for (int p = 0; p < 2; ++p) {
      int cbase = p * 256 + wave * 64;
      int chunk = cbase + lane;
      int r = chunk >> 2, cb = chunk & 3;
      gload16(A + (size_t)(rowBase + r) * K + k0 + cb * 8, (char*)As + cbase * 16);
      gload16(BT + (size_t)(colBase + r) * K + k0 + cb * 8, (char*)Bs + cbase * 16);
    }
    __syncthreads();
    bf16x8 a[4], b[4];
#pragma unroll
    for (int m = 0; m < 4; ++m)
      a[m] = *reinterpret_cast<const bf16x8*>(&As[(wr * 64 + m * 16 + fr) * 32 + fq * 8]);
#pragma unroll
    for (int n = 0; n < 4; ++n)
      b[n] = *reinterpret_cast<const bf16x8*>(&Bs[(wc * 64 + n * 16 + fr) * 32 + fq * 8]);
#pragma unroll
    for (int m = 0; m < 4; ++m)
#pragma unroll
      for (int n = 0; n < 4; ++n)
        acc[m][n] = __builtin_amdgcn_mfma_f32_16x16x32_bf16(a[m], b[n], acc[m][n], 0, 0, 0);
    __syncthreads();
  }
#pragma unroll
  for (int m = 0; m < 4; ++m) {
    int row0 = rowBase + wr * 64 + m * 16 + fq * 4;
#pragma unroll
    for (int n = 0; n < 4; ++n) {
      int col = colBase + wc * 64 + n * 16 + fr;
#pragma unroll
      for (int j = 0; j < 4; ++j) {
        if (OUT_BF16)
          ((u16*)C)[(size_t)(row0 + j) * N + col] = f2bf(acc[m][n][j]);
        else
          ((float*)C)[(size_t)(row0 + j) * N + col] = acc[m][n][j];
      }
    }
  }
}

// ---------------- flash attention (causal, GQA) ----------------
// 8 waves, 512 thr. Waves split: group A (0-3) = k-cols 0..63 of each KT=128
// step, group B (4-7) = k-cols 64..127; both cover the same 128 q-rows
// (4 pairs x 32q, swapped 32x32 MFMA + in-register softmax per wave).
// Independent online softmax per group; ONE flash-combine per q-tile through
// LDS. Serial q-tile pair {31-p, p}: every block exactly 33 steps ->
// 256 blocks = 1/CU, perfect balance, 8 waves/CU.
// __launch_bounds__(512, 2): 2 waves/EU -> 256-VGPR budget. R6's default
// heuristic capped at 120 VGPR and spilled o[]/qf to scratch (1.2GB WRITE_SIZE,
// 421MB FETCH); state needs ~180 regs.
// Qb [H][S][HD] (pre-scaled by 1/sqrt(HD)*LOG2E), Kb [KV][S][HD],
// VT [KV][HD][S], AO [S][H*HD]
__device__ __forceinline__ void stage_kv128(const u16* __restrict__ Kbk,
                                            const u16* __restrict__ VTk, int kb,
                                            char* KsB, char* VsB, int tid) {
#pragma unroll
  for (int it = 0; it < 4; ++it) {
    int slot = it * 512 + tid;
    int r = slot >> 4, cb = slot & 15;
    int cbs = cb ^ (r & 15);  // pre-swizzled source -> linear LDS dest (G21)
    gload16(Kbk + (size_t)(kb + r) * HD + cbs * 8, KsB + slot * 16);
    gload16(VTk + (size_t)r * S_LEN + kb + cbs * 8, VsB + slot * 16);
  }
}

__global__ __launch_bounds__(512, 2) void k_attn(const u16* __restrict__ Qb,
                                                 const u16* __restrict__ Kb,
                                                 const u16* __restrict__ VT,
                                                 u16* __restrict__ AO) {
  __shared__ __align__(16) u16 Ks[2][128 * 128];  // [k][d], ^(k&15) chunk swz, 64KB
  __shared__ __align__(16) u16 Vs[2][128 * 128];  // [d][k], ^(d&15) chunk swz, 64KB
  const int h = blockIdx.x;
  const int p = blockIdx.y;  // 0..15
  const int kv = h >> 2;
  const int tid = threadIdx.x, wave = tid >> 6, lane = tid & 63;
  const int grp = wave >> 2, pr = wave & 3;  // k-group, q-pair
  const int ql = lane & 31, hi = lane >> 5;
  const float DEFER_THR = 11.541560327111707f;  // 8 * log2(e)

  const u16* Kbk = Kb + (size_t)kv * S_LEN * HD;
  const u16* VTk = VT + (size_t)kv * HD * S_LEN;

#pragma unroll 1
  for (int half = 0; half < 2; ++half) {
    const int qt = half ? p : (31 - p);
    const int qg0w = qt * 128 + pr * 32;  // wave's first q row
    const int qglob = qg0w + ql;          // this lane's q row

    __syncthreads();  // prior combine readers done before restaging Ks/Vs
    stage_kv128(Kbk, VTk, 0, (char*)Ks[0], (char*)Vs[0], tid);

    // Q as B-operand frags: lane(ql,hi) holds Q[qglob][t*16 + hi*8 + e]
    bf16x8 qf[8];
    {
      const u16* qp = Qb + ((size_t)h * S_LEN + qglob) * HD;
#pragma unroll
      for (int t = 0; t < 8; ++t)
        qf[t] = *reinterpret_cast<const bf16x8*>(qp + t * 16 + hi * 8);
    }
    f32x16 o[4] = {};  // O^T: lane(q=ql,hi) holds O[q][d0*32+(r&3)+8*(r>>2)+4*hi]
    float m = -INFINITY, l = 0.f;

    __syncthreads();  // tile 0 staged

    int buf = 0;
    const int nkt = qt + 1;
    for (int kt = 0; kt < nkt; ++kt) {
      if (kt + 1 < nkt)
        stage_kv128(Kbk, VTk, (kt + 1) * 128, (char*)Ks[buf ^ 1], (char*)Vs[buf ^ 1], tid);
      const int kbg = kt * 128 + grp * 64;  // this group's k base
      if (kbg <= qg0w + 31) {               // wave has >=1 unmasked column
        const char* Kc = (const char*)Ks[buf];
        const char* Vc = (const char*)Vs[buf];

        // S^T = mfma(A=K rows, B=Q): st0 = group k 0..31, st1 = 32..63
        f32x16 st0 = {}, st1 = {};
#pragma unroll
        for (int t = 0; t < 8; ++t) {
          int ch = (2 * t + hi) ^ (ql & 15);
          const int r0 = grp * 64 + ql, r1 = grp * 64 + 32 + ql;
          bf16x8 kf0 = *reinterpret_cast<const bf16x8*>(Kc + r0 * 256 + ch * 16);
          bf16x8 kf1 = *reinterpret_cast<const bf16x8*>(Kc + r1 * 256 + ch * 16);
          st0 = __builtin_amdgcn_mfma_f32_32x32x16_bf16(kf0, qf[t], st0, 0, 0, 0);
          st1 = __builtin_amdgcn_mfma_f32_32x32x16_bf16(kf1, qf[t], st1, 0, 0, 0);
        }
        // causal mask: lane reg r holds k_local = (r&3)+8*(r>>2)+4*hi
        if (kbg + 63 > qg0w) {
#pragma unroll
          for (int r = 0; r < 16; ++r) {
            int kl = (r & 3) + 8 * (r >> 2) + 4 * hi;
            if (kbg + kl > qglob) st0[r] = -1e30f;
            if (kbg + 32 + kl > qglob) st1[r] = -1e30f;
          }
        }
        // row max: in-lane tree over 32 values, then lane-pair combine (xor 32)
        float mx[16];
#pragma unroll
        for (int r = 0; r < 16; ++r) mx[r] = fmaxf(st0[r], st1[r]);
#pragma unroll
        for (int s = 8; s > 0; s >>= 1)
#pragma unroll
          for (int r = 0; r < 16; ++r)
            if (r < s) mx[r] = fmaxf(mx[r], mx[r + s]);
        float tmax = fmaxf(mx[0], __shfl_xor(mx[0], 32));
        // defer-max (T13)
        if (__any(tmax - m > DEFER_THR)) {
          float mn = fmaxf(m, tmax);
          float corr = exp2f(m - mn);
          m = mn;
          l *= corr;
#pragma unroll
          for (int d0 = 0; d0 < 4; ++d0) o[d0] *= corr;
        }
        // P = exp2(S - m); in-lane sum + lane-pair combine
        float sm[16];
#pragma unroll
        for (int r = 0; r < 16; ++r) {
          st0[r] = exp2f(st0[r] - m);
          st1[r] = exp2f(st1[r] - m);
          sm[r] = st0[r] + st1[r];
        }
#pragma unroll
        for (int s = 8; s > 0; s >>= 1)
#pragma unroll
          for (int r = 0; r < 16; ++r)
            if (r < s) sm[r] += sm[r + s];
        l += sm[0] + __shfl_xor(sm[0], 32);

        // P -> bf16 B-frags in-register (pack + shfl_xor(32) + select).
        // Frag slot (hi,e) holds P[q][kc*16 + hi*8 + e] (k local to group).
        bf16x8 pa[4];
#pragma unroll
        for (int kc = 0; kc < 4; ++kc) {
          int rb = 8 * (kc & 1);
          u32 w0, w1, w2, w3;
          if (kc < 2) {
            w0 = pk2(st0[rb + 0], st0[rb + 1]);
            w1 = pk2(st0[rb + 2], st0[rb + 3]);
            w2 = pk2(st0[rb + 4], st0[rb + 5]);
            w3 = pk2(st0[rb + 6], st0[rb + 7]);
          } else {
            w0 = pk2(st1[rb + 0], st1[rb + 1]);
            w1 = pk2(st1[rb + 2], st1[rb + 3]);
            w2 = pk2(st1[rb + 4], st1[rb + 5]);
            w3 = pk2(st1[rb + 6], st1[rb + 7]);
          }
          u32 xw0 = (u32)__shfl_xor((int)w0, 32);
          u32 xw1 = (u32)__shfl_xor((int)w1, 32);
          u32 xw2 = (u32)__shfl_xor((int)w2, 32);
          u32 xw3 = (u32)__shfl_xor((int)w3, 32);
          i32x4 pw;
          pw[0] = (int)(hi ? xw2 : w0);
          pw[1] = (int)(hi ? xw3 : w1);
          pw[2] = (int)(hi ? w2 : xw0);
          pw[3] = (int)(hi ? w3 : xw1);
          pa[kc] = __builtin_bit_cast(bf16x8, pw);
        }
        // O^T += mfma(A=V^T rows, B=P^T) over this group's 64 k-cols
#pragma unroll
        for (int d0 = 0; d0 < 4; ++d0) {
          int dr = d0 * 32 + ql;
#pragma unroll
          for (int kc = 0; kc < 4; ++kc) {
            int ch = (grp * 8 + 2 * kc + hi) ^ (ql & 15);
            bf16x8 vf = *reinterpret_cast<const bf16x8*>(Vc + dr * 256 + ch * 16);
            o[d0] = __builtin_amdgcn_mfma_f32_32x32x16_bf16(vf, pa[kc], o[d0], 0, 0, 0);
          }
        }
      }
      __syncthreads();  // next tile staged; buf safe to flip
      buf ^= 1;
    }

    // ---- flash-combine of the two k-groups (once per q-tile) ----
    // Group A merges+stores d0 {0,1}, writes o[2],o[3]; group B the reverse.
    const int mbase = grp ? 2 : 0;
    const int wbase = grp ? 0 : 2;
    float2* exch = (float2*)Ks;  // [d0 4][rp 8][pr 4][lane 64] float2 = 64KB
    float2* mlb = (float2*)Vs;   // [grp 2][pr 4][ql 32] float2
#pragma unroll
    for (int i = 0; i < 2; ++i)
#pragma unroll
      for (int rp = 0; rp < 8; ++rp) {
        int d0 = wbase + i;
        float2 v;
        v.x = o[d0][2 * rp];
        v.y = o[d0][2 * rp + 1];
        exch[((d0 * 8 + rp) * 4 + pr) * 64 + lane] = v;
      }
    if (hi == 0) {
      float2 v;
      v.x = m;
      v.y = l;
      mlb[(grp * 4 + pr) * 32 + ql] = v;
    }
    __syncthreads();
    {
      float2 pml = mlb[((1 - grp) * 4 + pr) * 32 + ql];
      float mm = fmaxf(m, pml.x);
      float fa = exp2f(m - mm), fb = exp2f(pml.x - mm);
      float ll = l * fa + pml.y * fb;
      float inv = 1.0f / ll;
      u16* aoRow = AO + (size_t)qglob * DMODEL + h * HD;
#pragma unroll
      for (int i = 0; i < 2; ++i)
#pragma unroll
        for (int rp = 0; rp < 8; ++rp) {
          int d0 = mbase + i;
          float2 po = exch[((d0 * 8 + rp) * 4 + pr) * 64 + lane];
          int r = 2 * rp;
          float u0 = (o[d0][r] * fa + po.x * fb) * inv;
          float u1 = (o[d0][r + 1] * fa + po.y * fb) * inv;
          int d = d0 * 32 + (r & 3) + 8 * (r >> 2) + 4 * hi;
          *reinterpret_cast<u32*>(aoRow + d) = pk2(u0, u1);
        }
    }
    // loop-top __syncthreads protects Ks/Vs before next tile's staging
  }
}

// ---------------- launch ----------------
extern "C" void kernel_launch(void* const* d_in, const int* in_sizes, int n_in,
                              void* d_out, int out_size, void* d_ws, size_t ws_size,
                              hipStream_t stream) {
  const float* hidden = (const float*)d_in[0];
  const float* Wq = (const float*)d_in[1];
  const float* Wk = (const float*)d_in[2];
  const float* Wv = (const float*)d_in[3];
  const float* Wo = (const float*)d_in[4];
  // d_in[5] = attention_mask: causal, applied analytically (unused)
  const int* pos_ids = (const int*)d_in[6];
  float* out = (float*)d_out;

  char* ws = (char*)d_ws;
  u16* Xb   = (u16*)(ws);                               // [4096][2048]   16MB
  u16* Wt   = (u16*)(ws + (16ull << 20));               // [3072][2048]   12MB
  u16* WoT  = (u16*)(ws + (28ull << 20));               // [2048][2048]    8MB
  u16* QKVb = (u16*)(ws + (36ull << 20));               // [4096][3072]   24MB
  u16* Qb   = (u16*)(ws + (60ull << 20));               // [16][4096][128] 16MB
  u16* Kb   = (u16*)(ws + (76ull << 20));               // [4][4096][128]   4MB
  u16* VT   = (u16*)(ws + (80ull << 20));               // [4][128][4096]   4MB
  u16* AO   = QKVb;  // alias: QKVb fully consumed before attention writes AO

  dim3 tb(32, 8);
  k_f32_to_bf16<<<dim3((S_LEN * DMODEL / 4) / 256), dim3(256), 0, stream>>>(
      hidden, Xb, S_LEN * DMODEL / 4);
  k_transpose_f32_bf16<<<dim3(64, 64), tb, 0, stream>>>(Wq, 2048, Wt, 2048);
  k_transpose_f32_bf16<<<dim3(16, 64), tb, 0, stream>>>(Wk, 512, Wt + (size_t)2048 * 2048, 2048);
  k_transpose_f32_bf16<<<dim3(16, 64), tb, 0, stream>>>(Wv, 512, Wt + (size_t)2560 * 2048, 2048);
  k_transpose_f32_bf16<<<dim3(64, 64), tb, 0, stream>>>(Wo, 2048, WoT, 2048);

  k_gemm_bt<1><<<dim3(24, 32), 256, 0, stream>>>(Xb, Wt, QKVb, S_LEN, NQKV, DMODEL);

  k_rope<<<dim3(S_LEN), 256, 0, stream>>>(QKVb, pos_ids, Qb, Kb);
  k_transpose_bf16<<<dim3(16, 128), tb, 0, stream>>>(QKVb + 2560, NQKV, VT, S_LEN);

  k_attn<<<dim3(NH, 16), 512, 0, stream>>>(Qb, Kb, VT, AO);

  k_gemm_bt<0><<<dim3(16, 32), 256, 0, stream>>>(AO, WoT, out, S_LEN, DMODEL, DMODEL);
}

// Round 8
// 286.574 us; speedup vs baseline: 1.8598x; 1.8583x over previous
//
#include <hip/hip_runtime.h>
#include <hip/hip_bf16.h>
#include <cstdint>
#include <cmath>

#define S_LEN 4096
#define DMODEL 2048
#define NH 16
#define NKV 4
#define HD 128
#define NQKV 3072  // 2048 Q + 512 K + 512 V

typedef unsigned short u16;
typedef unsigned int u32;
typedef __attribute__((ext_vector_type(8))) __bf16 bf16x8;
typedef __attribute__((ext_vector_type(4))) float f32x4;
typedef __attribute__((ext_vector_type(16))) float f32x16;
typedef __attribute__((ext_vector_type(4))) int i32x4;

__device__ __forceinline__ u16 f2bf(float f) {
  __bf16 h = (__bf16)f;  // RNE
  return __builtin_bit_cast(u16, h);
}
__device__ __forceinline__ float bf2f(u16 u) {
  return (float)__builtin_bit_cast(__bf16, u);
}
// pack two f32 -> u32 of two bf16 (lo=a, hi=b); scalar casts, compiler fuses
__device__ __forceinline__ u32 pk2(float a, float b) {
  return (u32)f2bf(a) | ((u32)f2bf(b) << 16);
}

__device__ __forceinline__ void gload16(const void* g, void* l) {
  __builtin_amdgcn_global_load_lds(
      (const __attribute__((address_space(1))) void*)g,
      (__attribute__((address_space(3))) void*)l, 16, 0, 0);
}

// ---------------- pack / convert ----------------
__global__ void k_f32_to_bf16(const float* __restrict__ src, u16* __restrict__ dst, int n4) {
  int i = blockIdx.x * blockDim.x + threadIdx.x;
  if (i < n4) {
    float4 v = reinterpret_cast<const float4*>(src)[i];
    ushort4 o = make_ushort4(f2bf(v.x), f2bf(v.y), f2bf(v.z), f2bf(v.w));
    reinterpret_cast<ushort4*>(dst)[i] = o;
  }
}

// dst[n][k] = bf16(src[k][n])
__global__ void k_transpose_f32_bf16(const float* __restrict__ src, int srcStride,
                                     u16* __restrict__ dst, int dstStride) {
  __shared__ float tile[32][33];
  int n0 = blockIdx.x * 32, k0 = blockIdx.y * 32;
  int tx = threadIdx.x, ty = threadIdx.y;  // 32 x 8
#pragma unroll
  for (int r = 0; r < 32; r += 8)
    tile[ty + r][tx] = src[(size_t)(k0 + ty + r) * srcStride + n0 + tx];
  __syncthreads();
#pragma unroll
  for (int r = 0; r < 32; r += 8)
    dst[(size_t)(n0 + ty + r) * dstStride + k0 + tx] = f2bf(tile[tx][ty + r]);
}

__global__ void k_transpose_bf16(const u16* __restrict__ src, int srcStride,
                                 u16* __restrict__ dst, int dstStride) {
  __shared__ u16 tile[32][33];
  int n0 = blockIdx.x * 32, k0 = blockIdx.y * 32;
  int tx = threadIdx.x, ty = threadIdx.y;  // 32 x 8
#pragma unroll
  for (int r = 0; r < 32; r += 8)
    tile[ty + r][tx] = src[(size_t)(k0 + ty + r) * srcStride + n0 + tx];
  __syncthreads();
#pragma unroll
  for (int r = 0; r < 32; r += 8)
    dst[(size_t)(n0 + ty + r) * dstStride + k0 + tx] = tile[tx][ty + r];
}

// ---------------- RoPE ----------------
// Q gets 1/sqrt(HD) * LOG2E folded in (softmax runs in exp2 domain).
__global__ void k_rope(const u16* __restrict__ qkv, const int* __restrict__ pos_ids,
                       u16* __restrict__ Qb, u16* __restrict__ Kb) {
  int s = blockIdx.x;
  float pos = (float)pos_ids[s];
  const u16* row = qkv + (size_t)s * NQKV;
  const float L2B = 13.287712379549449f;  // log2(10000)
  const float QSCALE = 0.08838834764831845f * 1.4426950408889634f;
  for (int c = threadIdx.x; c < DMODEL + NKV * HD; c += blockDim.x) {
    int d = c & 127;
    int dh = d & 63;
    float invf = exp2f(-(float)dh * (L2B / 64.0f));
    float ang = pos * invf;
    float cv = cosf(ang), sv = sinf(ang);
    float x = bf2f(row[c]);
    float xp = bf2f(row[c ^ 64]);
    float rot = (d < 64) ? -xp : xp;
    float out = x * cv + rot * sv;
    if (c < DMODEL) {
      int h = c >> 7;
      out *= QSCALE;
      Qb[((size_t)h * S_LEN + s) * HD + d] = f2bf(out);
    } else {
      int kvh = (c - DMODEL) >> 7;
      Kb[((size_t)kvh * S_LEN + s) * HD + d] = f2bf(out);
    }
  }
}

// ---------------- m97-style 128x128 GEMM, B^T operand ----------------
template <int OUT_BF16>
__global__ __launch_bounds__(256) void k_gemm_bt(const u16* __restrict__ A,
                                                 const u16* __restrict__ BT,
                                                 void* __restrict__ C, int M, int N, int K) {
  __shared__ __align__(16) u16 As[128 * 32];
  __shared__ __align__(16) u16 Bs[128 * 32];
  const int tid = threadIdx.x, wave = tid >> 6, lane = tid & 63;
  const int fr = lane & 15, fq = lane >> 4;
  const int rowBase = blockIdx.y * 128, colBase = blockIdx.x * 128;
  const int wr = wave >> 1, wc = wave & 1;
  f32x4 acc[4][4] = {};
  const int nk = K >> 5;
  for (int kt = 0; kt < nk; ++kt) {
    const int k0 = kt << 5;
#pragma unroll
    for (int p = 0; p < 2; ++p) {
      int cbase = p * 256 + wave * 64;
      int chunk = cbase + lane;
      int r = chunk >> 2, cb = chunk & 3;
      gload16(A + (size_t)(rowBase + r) * K + k0 + cb * 8, (char*)As + cbase * 16);
      gload16(BT + (size_t)(colBase + r) * K + k0 + cb * 8, (char*)Bs + cbase * 16);
    }
    __syncthreads();
    bf16x8 a[4], b[4];
#pragma unroll
    for (int m = 0; m < 4; ++m)
      a[m] = *reinterpret_cast<const bf16x8*>(&As[(wr * 64 + m * 16 + fr) * 32 + fq * 8]);
#pragma unroll
    for (int n = 0; n < 4; ++n)
      b[n] = *reinterpret_cast<const bf16x8*>(&Bs[(wc * 64 + n * 16 + fr) * 32 + fq * 8]);
#pragma unroll
    for (int m = 0; m < 4; ++m)
#pragma unroll
      for (int n = 0; n < 4; ++n)
        acc[m][n] = __builtin_amdgcn_mfma_f32_16x16x32_bf16(a[m], b[n], acc[m][n], 0, 0, 0);
    __syncthreads();
  }
#pragma unroll
  for (int m = 0; m < 4; ++m) {
    int row0 = rowBase + wr * 64 + m * 16 + fq * 4;
#pragma unroll
    for (int n = 0; n < 4; ++n) {
      int col = colBase + wc * 64 + n * 16 + fr;
#pragma unroll
      for (int j = 0; j < 4; ++j) {
        if (OUT_BF16)
          ((u16*)C)[(size_t)(row0 + j) * N + col] = f2bf(acc[m][n][j]);
        else
          ((float*)C)[(size_t)(row0 + j) * N + col] = acc[m][n][j];
      }
    }
  }
}

// ---------------- flash attention (causal, GQA) ----------------
// 8 waves, 512 thr. Group A (waves 0-3) = k-cols 0..63 of each KT=128 step,
// group B (4-7) = k-cols 64..127; both cover the same 128 q-rows (4 pairs x
// 32q, swapped 32x32 MFMA + in-register softmax per wave). Independent online
// softmax per group; ONE flash-combine per q-tile through LDS. Serial q-tile
// pair {31-p, p}: every block exactly 33 steps -> 256 blocks = 1/CU.
// RULE #20 (R6/R7 bug): o[] must ONLY be indexed with compile-time constants.
// o[wbase+i] (runtime grp) forced ALL of o[] into scratch: VGPR=120, 421MB
// FETCH + 1.2GB WRITE/dispatch, 5x slowdown. Combine now branches on the
// wave-uniform grp with static indices in each branch.
// Qb [H][S][HD] (pre-scaled by 1/sqrt(HD)*LOG2E), Kb [KV][S][HD],
// VT [KV][HD][S], AO [S][H*HD]
__device__ __forceinline__ void stage_kv128(const u16* __restrict__ Kbk,
                                            const u16* __restrict__ VTk, int kb,
                                            char* KsB, char* VsB, int tid) {
#pragma unroll
  for (int it = 0; it < 4; ++it) {
    int slot = it * 512 + tid;
    int r = slot >> 4, cb = slot & 15;
    int cbs = cb ^ (r & 15);  // pre-swizzled source -> linear LDS dest (G21)
    gload16(Kbk + (size_t)(kb + r) * HD + cbs * 8, KsB + slot * 16);
    gload16(VTk + (size_t)r * S_LEN + kb + cbs * 8, VsB + slot * 16);
  }
}

__global__ __launch_bounds__(512, 2) void k_attn(const u16* __restrict__ Qb,
                                                 const u16* __restrict__ Kb,
                                                 const u16* __restrict__ VT,
                                                 u16* __restrict__ AO) {
  __shared__ __align__(16) u16 Ks[2][128 * 128];  // [k][d], ^(k&15) chunk swz, 64KB
  __shared__ __align__(16) u16 Vs[2][128 * 128];  // [d][k], ^(d&15) chunk swz, 64KB
  const int h = blockIdx.x;
  const int p = blockIdx.y;  // 0..15
  const int kv = h >> 2;
  const int tid = threadIdx.x, wave = tid >> 6, lane = tid & 63;
  const int grp = wave >> 2, pr = wave & 3;  // k-group, q-pair
  const int ql = lane & 31, hi = lane >> 5;
  const float DEFER_THR = 11.541560327111707f;  // 8 * log2(e)

  const u16* Kbk = Kb + (size_t)kv * S_LEN * HD;
  const u16* VTk = VT + (size_t)kv * HD * S_LEN;

#pragma unroll 1
  for (int half = 0; half < 2; ++half) {
    const int qt = half ? p : (31 - p);
    const int qg0w = qt * 128 + pr * 32;  // wave's first q row
    const int qglob = qg0w + ql;          // this lane's q row

    __syncthreads();  // prior combine readers done before restaging Ks/Vs
    stage_kv128(Kbk, VTk, 0, (char*)Ks[0], (char*)Vs[0], tid);

    // Q as B-operand frags: lane(ql,hi) holds Q[qglob][t*16 + hi*8 + e]
    bf16x8 qf[8];
    {
      const u16* qp = Qb + ((size_t)h * S_LEN + qglob) * HD;
#pragma unroll
      for (int t = 0; t < 8; ++t)
        qf[t] = *reinterpret_cast<const bf16x8*>(qp + t * 16 + hi * 8);
    }
    f32x16 o[4] = {};  // O^T: lane(q=ql,hi) holds O[q][d0*32+(r&3)+8*(r>>2)+4*hi]
    float m = -INFINITY, l = 0.f;

    __syncthreads();  // tile 0 staged

    int buf = 0;
    const int nkt = qt + 1;
    for (int kt = 0; kt < nkt; ++kt) {
      if (kt + 1 < nkt)
        stage_kv128(Kbk, VTk, (kt + 1) * 128, (char*)Ks[buf ^ 1], (char*)Vs[buf ^ 1], tid);
      const int kbg = kt * 128 + grp * 64;  // this group's k base
      if (kbg <= qg0w + 31) {               // wave has >=1 unmasked column
        const char* Kc = (const char*)Ks[buf];
        const char* Vc = (const char*)Vs[buf];

        // S^T = mfma(A=K rows, B=Q): st0 = group k 0..31, st1 = 32..63
        f32x16 st0 = {}, st1 = {};
#pragma unroll
        for (int t = 0; t < 8; ++t) {
          int ch = (2 * t + hi) ^ (ql & 15);
          const int r0 = grp * 64 + ql, r1 = grp * 64 + 32 + ql;
          bf16x8 kf0 = *reinterpret_cast<const bf16x8*>(Kc + r0 * 256 + ch * 16);
          bf16x8 kf1 = *reinterpret_cast<const bf16x8*>(Kc + r1 * 256 + ch * 16);
          st0 = __builtin_amdgcn_mfma_f32_32x32x16_bf16(kf0, qf[t], st0, 0, 0, 0);
          st1 = __builtin_amdgcn_mfma_f32_32x32x16_bf16(kf1, qf[t], st1, 0, 0, 0);
        }
        // causal mask: lane reg r holds k_local = (r&3)+8*(r>>2)+4*hi
        if (kbg + 63 > qg0w) {
#pragma unroll
          for (int r = 0; r < 16; ++r) {
            int kl = (r & 3) + 8 * (r >> 2) + 4 * hi;
            if (kbg + kl > qglob) st0[r] = -1e30f;
            if (kbg + 32 + kl > qglob) st1[r] = -1e30f;
          }
        }
        // row max: in-lane tree over 32 values, then lane-pair combine (xor 32)
        float mx[16];
#pragma unroll
        for (int r = 0; r < 16; ++r) mx[r] = fmaxf(st0[r], st1[r]);
#pragma unroll
        for (int s = 8; s > 0; s >>= 1)
#pragma unroll
          for (int r = 0; r < 16; ++r)
            if (r < s) mx[r] = fmaxf(mx[r], mx[r + s]);
        float tmax = fmaxf(mx[0], __shfl_xor(mx[0], 32));
        // defer-max (T13)
        if (__any(tmax - m > DEFER_THR)) {
          float mn = fmaxf(m, tmax);
          float corr = exp2f(m - mn);
          m = mn;
          l *= corr;
#pragma unroll
          for (int d0 = 0; d0 < 4; ++d0) o[d0] *= corr;
        }
        // P = exp2(S - m); in-lane sum + lane-pair combine
        float sm[16];
#pragma unroll
        for (int r = 0; r < 16; ++r) {
          st0[r] = exp2f(st0[r] - m);
          st1[r] = exp2f(st1[r] - m);
          sm[r] = st0[r] + st1[r];
        }
#pragma unroll
        for (int s = 8; s > 0; s >>= 1)
#pragma unroll
          for (int r = 0; r < 16; ++r)
            if (r < s) sm[r] += sm[r + s];
        l += sm[0] + __shfl_xor(sm[0], 32);

        // P -> bf16 B-frags in-register (pack + shfl_xor(32) + select).
        // Frag slot (hi,e) holds P[q][kc*16 + hi*8 + e] (k local to group).
        bf16x8 pa[4];
#pragma unroll
        for (int kc = 0; kc < 4; ++kc) {
          int rb = 8 * (kc & 1);
          u32 w0, w1, w2, w3;
          if (kc < 2) {
            w0 = pk2(st0[rb + 0], st0[rb + 1]);
            w1 = pk2(st0[rb + 2], st0[rb + 3]);
            w2 = pk2(st0[rb + 4], st0[rb + 5]);
            w3 = pk2(st0[rb + 6], st0[rb + 7]);
          } else {
            w0 = pk2(st1[rb + 0], st1[rb + 1]);
            w1 = pk2(st1[rb + 2], st1[rb + 3]);
            w2 = pk2(st1[rb + 4], st1[rb + 5]);
            w3 = pk2(st1[rb + 6], st1[rb + 7]);
          }
          u32 xw0 = (u32)__shfl_xor((int)w0, 32);
          u32 xw1 = (u32)__shfl_xor((int)w1, 32);
          u32 xw2 = (u32)__shfl_xor((int)w2, 32);
          u32 xw3 = (u32)__shfl_xor((int)w3, 32);
          i32x4 pw;
          pw[0] = (int)(hi ? xw2 : w0);
          pw[1] = (int)(hi ? xw3 : w1);
          pw[2] = (int)(hi ? w2 : xw0);
          pw[3] = (int)(hi ? w3 : xw1);
          pa[kc] = __builtin_bit_cast(bf16x8, pw);
        }
        // O^T += mfma(A=V^T rows, B=P^T) over this group's 64 k-cols
#pragma unroll
        for (int d0 = 0; d0 < 4; ++d0) {
          int dr = d0 * 32 + ql;
#pragma unroll
          for (int kc = 0; kc < 4; ++kc) {
            int ch = (grp * 8 + 2 * kc + hi) ^ (ql & 15);
            bf16x8 vf = *reinterpret_cast<const bf16x8*>(Vc + dr * 256 + ch * 16);
            o[d0] = __builtin_amdgcn_mfma_f32_32x32x16_bf16(vf, pa[kc], o[d0], 0, 0, 0);
          }
        }
      }
      __syncthreads();  // next tile staged; buf safe to flip
      buf ^= 1;
    }

    // ---- flash-combine of the two k-groups (once per q-tile) ----
    // grp 0: stores o[2],o[3] for partner, merges+writes d0 0,1.
    // grp 1: stores o[0],o[1] for partner, merges+writes d0 2,3.
    // STATIC o[] indices only (rule #20) — branch on wave-uniform grp.
    float2* exch = (float2*)Ks;  // [d0 4][rp 8][pr 4][lane 64] float2 = 64KB
    float2* mlb = (float2*)Vs;   // [grp 2][pr 4][ql 32] float2
    if (grp == 0) {
#pragma unroll
      for (int rp = 0; rp < 8; ++rp) {
        float2 v2, v3;
        v2.x = o[2][2 * rp]; v2.y = o[2][2 * rp + 1];
        v3.x = o[3][2 * rp]; v3.y = o[3][2 * rp + 1];
        exch[((2 * 8 + rp) * 4 + pr) * 64 + lane] = v2;
        exch[((3 * 8 + rp) * 4 + pr) * 64 + lane] = v3;
      }
    } else {
#pragma unroll
      for (int rp = 0; rp < 8; ++rp) {
        float2 v0, v1;
        v0.x = o[0][2 * rp]; v0.y = o[0][2 * rp + 1];
        v1.x = o[1][2 * rp]; v1.y = o[1][2 * rp + 1];
        exch[((0 * 8 + rp) * 4 + pr) * 64 + lane] = v0;
        exch[((1 * 8 + rp) * 4 + pr) * 64 + lane] = v1;
      }
    }
    if (hi == 0) {
      float2 v;
      v.x = m;
      v.y = l;
      mlb[(grp * 4 + pr) * 32 + ql] = v;
    }
    __syncthreads();
    {
      float2 pml = mlb[((1 - grp) * 4 + pr) * 32 + ql];
      float mm = fmaxf(m, pml.x);
      float fa = exp2f(m - mm), fb = exp2f(pml.x - mm);
      float ll = l * fa + pml.y * fb;
      float inv = 1.0f / ll;
      u16* aoRow = AO + (size_t)qglob * DMODEL + h * HD;
      if (grp == 0) {
#pragma unroll
        for (int rp = 0; rp < 8; ++rp) {
          int r = 2 * rp;
          int dbase = (r & 3) + 8 * (r >> 2) + 4 * hi;
          float2 po0 = exch[((0 * 8 + rp) * 4 + pr) * 64 + lane];
          float u0 = (o[0][r] * fa + po0.x * fb) * inv;
          float u1 = (o[0][r + 1] * fa + po0.y * fb) * inv;
          *reinterpret_cast<u32*>(aoRow + 0 * 32 + dbase) = pk2(u0, u1);
          float2 po1 = exch[((1 * 8 + rp) * 4 + pr) * 64 + lane];
          u0 = (o[1][r] * fa + po1.x * fb) * inv;
          u1 = (o[1][r + 1] * fa + po1.y * fb) * inv;
          *reinterpret_cast<u32*>(aoRow + 1 * 32 + dbase) = pk2(u0, u1);
        }
      } else {
#pragma unroll
        for (int rp = 0; rp < 8; ++rp) {
          int r = 2 * rp;
          int dbase = (r & 3) + 8 * (r >> 2) + 4 * hi;
          float2 po2 = exch[((2 * 8 + rp) * 4 + pr) * 64 + lane];
          float u0 = (o[2][r] * fa + po2.x * fb) * inv;
          float u1 = (o[2][r + 1] * fa + po2.y * fb) * inv;
          *reinterpret_cast<u32*>(aoRow + 2 * 32 + dbase) = pk2(u0, u1);
          float2 po3 = exch[((3 * 8 + rp) * 4 + pr) * 64 + lane];
          u0 = (o[3][r] * fa + po3.x * fb) * inv;
          u1 = (o[3][r + 1] * fa + po3.y * fb) * inv;
          *reinterpret_cast<u32*>(aoRow + 3 * 32 + dbase) = pk2(u0, u1);
        }
      }
    }
    // loop-top __syncthreads protects Ks/Vs before next tile's staging
  }
}

// ---------------- launch ----------------
extern "C" void kernel_launch(void* const* d_in, const int* in_sizes, int n_in,
                              void* d_out, int out_size, void* d_ws, size_t ws_size,
                              hipStream_t stream) {
  const float* hidden = (const float*)d_in[0];
  const float* Wq = (const float*)d_in[1];
  const float* Wk = (const float*)d_in[2];
  const float* Wv = (const float*)d_in[3];
  const float* Wo = (const float*)d_in[4];
  // d_in[5] = attention_mask: causal, applied analytically (unused)
  const int* pos_ids = (const int*)d_in[6];
  float* out = (float*)d_out;

  char* ws = (char*)d_ws;
  u16* Xb   = (u16*)(ws);                               // [4096][2048]   16MB
  u16* Wt   = (u16*)(ws + (16ull << 20));               // [3072][2048]   12MB
  u16* WoT  = (u16*)(ws + (28ull << 20));               // [2048][2048]    8MB
  u16* QKVb = (u16*)(ws + (36ull << 20));               // [4096][3072]   24MB
  u16* Qb   = (u16*)(ws + (60ull << 20));               // [16][4096][128] 16MB
  u16* Kb   = (u16*)(ws + (76ull << 20));               // [4][4096][128]   4MB
  u16* VT   = (u16*)(ws + (80ull << 20));               // [4][128][4096]   4MB
  u16* AO   = QKVb;  // alias: QKVb fully consumed before attention writes AO

  dim3 tb(32, 8);
  k_f32_to_bf16<<<dim3((S_LEN * DMODEL / 4) / 256), dim3(256), 0, stream>>>(
      hidden, Xb, S_LEN * DMODEL / 4);
  k_transpose_f32_bf16<<<dim3(64, 64), tb, 0, stream>>>(Wq, 2048, Wt, 2048);
  k_transpose_f32_bf16<<<dim3(16, 64), tb, 0, stream>>>(Wk, 512, Wt + (size_t)2048 * 2048, 2048);
  k_transpose_f32_bf16<<<dim3(16, 64), tb, 0, stream>>>(Wv, 512, Wt + (size_t)2560 * 2048, 2048);
  k_transpose_f32_bf16<<<dim3(64, 64), tb, 0, stream>>>(Wo, 2048, WoT, 2048);

  k_gemm_bt<1><<<dim3(24, 32), 256, 0, stream>>>(Xb, Wt, QKVb, S_LEN, NQKV, DMODEL);

  k_rope<<<dim3(S_LEN), 256, 0, stream>>>(QKVb, pos_ids, Qb, Kb);
  k_transpose_bf16<<<dim3(16, 128), tb, 0, stream>>>(QKVb + 2560, NQKV, VT, S_LEN);

  k_attn<<<dim3(NH, 16), 512, 0, stream>>>(Qb, Kb, VT, AO);

  k_gemm_bt<0><<<dim3(16, 32), 256, 0, stream>>>(AO, WoT, out, S_LEN, DMODEL, DMODEL);
}

// Round 11
// 281.395 us; speedup vs baseline: 1.8940x; 1.0184x over previous
//
#include <hip/hip_runtime.h>
#include <hip/hip_bf16.h>
#include <cstdint>
#include <cmath>

#define S_LEN 4096
#define DMODEL 2048
#define NH 16
#define NKV 4
#define HD 128
#define NQKV 3072  // 2048 Q + 512 K + 512 V

typedef unsigned short u16;
typedef unsigned int u32;
typedef __attribute__((ext_vector_type(8))) __bf16 bf16x8;
typedef __attribute__((ext_vector_type(4))) float f32x4;
typedef __attribute__((ext_vector_type(16))) float f32x16;
typedef __attribute__((ext_vector_type(4))) int i32x4;

__device__ __forceinline__ u16 f2bf(float f) {
  __bf16 h = (__bf16)f;  // RNE
  return __builtin_bit_cast(u16, h);
}
__device__ __forceinline__ float bf2f(u16 u) {
  return (float)__builtin_bit_cast(__bf16, u);
}
// pack two f32 -> u32 of two bf16 (lo=a, hi=b); scalar casts, compiler fuses
__device__ __forceinline__ u32 pk2(float a, float b) {
  return (u32)f2bf(a) | ((u32)f2bf(b) << 16);
}

__device__ __forceinline__ void gload16(const void* g, void* l) {
  __builtin_amdgcn_global_load_lds(
      (const __attribute__((address_space(1))) void*)g,
      (__attribute__((address_space(3))) void*)l, 16, 0, 0);
}

// ---------------- pack / convert ----------------
__global__ void k_f32_to_bf16(const float* __restrict__ src, u16* __restrict__ dst, int n4) {
  int i = blockIdx.x * blockDim.x + threadIdx.x;
  if (i < n4) {
    float4 v = reinterpret_cast<const float4*>(src)[i];
    ushort4 o = make_ushort4(f2bf(v.x), f2bf(v.y), f2bf(v.z), f2bf(v.w));
    reinterpret_cast<ushort4*>(dst)[i] = o;
  }
}

// dst[n][k] = bf16(src[k][n])
__global__ void k_transpose_f32_bf16(const float* __restrict__ src, int srcStride,
                                     u16* __restrict__ dst, int dstStride) {
  __shared__ float tile[32][33];
  int n0 = blockIdx.x * 32, k0 = blockIdx.y * 32;
  int tx = threadIdx.x, ty = threadIdx.y;  // 32 x 8
#pragma unroll
  for (int r = 0; r < 32; r += 8)
    tile[ty + r][tx] = src[(size_t)(k0 + ty + r) * srcStride + n0 + tx];
  __syncthreads();
#pragma unroll
  for (int r = 0; r < 32; r += 8)
    dst[(size_t)(n0 + ty + r) * dstStride + k0 + tx] = f2bf(tile[tx][ty + r]);
}

__global__ void k_transpose_bf16(const u16* __restrict__ src, int srcStride,
                                 u16* __restrict__ dst, int dstStride) {
  __shared__ u16 tile[32][33];
  int n0 = blockIdx.x * 32, k0 = blockIdx.y * 32;
  int tx = threadIdx.x, ty = threadIdx.y;  // 32 x 8
#pragma unroll
  for (int r = 0; r < 32; r += 8)
    tile[ty + r][tx] = src[(size_t)(k0 + ty + r) * srcStride + n0 + tx];
  __syncthreads();
#pragma unroll
  for (int r = 0; r < 32; r += 8)
    dst[(size_t)(n0 + ty + r) * dstStride + k0 + tx] = tile[tx][ty + r];
}

// ---------------- RoPE ----------------
// Trig table: one sincos per (s, dh) instead of per element (40x fewer).
__global__ void k_rope_tab(const int* __restrict__ pos_ids, float2* __restrict__ tab) {
  int idx = blockIdx.x * blockDim.x + threadIdx.x;  // 4096*64
  int s = idx >> 6, dh = idx & 63;
  const float L2B = 13.287712379549449f;  // log2(10000)
  float pos = (float)pos_ids[s];
  float invf = exp2f(-(float)dh * (L2B / 64.0f));
  float ang = pos * invf;
  tab[idx] = make_float2(cosf(ang), sinf(ang));
}

// Q gets 1/sqrt(HD) * LOG2E folded in (softmax runs in exp2 domain).
__global__ void k_rope(const u16* __restrict__ qkv, const float2* __restrict__ tab,
                       u16* __restrict__ Qb, u16* __restrict__ Kb) {
  int s = blockIdx.x;
  const u16* row = qkv + (size_t)s * NQKV;
  const float QSCALE = 0.08838834764831845f * 1.4426950408889634f;
  for (int c = threadIdx.x; c < DMODEL + NKV * HD; c += blockDim.x) {
    int d = c & 127;
    int dh = d & 63;
    float2 cs = tab[s * 64 + dh];
    float x = bf2f(row[c]);
    float xp = bf2f(row[c ^ 64]);
    float rot = (d < 64) ? -xp : xp;
    float out = x * cs.x + rot * cs.y;
    if (c < DMODEL) {
      int h = c >> 7;
      out *= QSCALE;
      Qb[((size_t)h * S_LEN + s) * HD + d] = f2bf(out);
    } else {
      int kvh = (c - DMODEL) >> 7;
      Kb[((size_t)kvh * S_LEN + s) * HD + d] = f2bf(out);
    }
  }
}

// ---------------- m97-style 128x128 GEMM, B^T operand ----------------
template <int OUT_BF16>
__global__ __launch_bounds__(256) void k_gemm_bt(const u16* __restrict__ A,
                                                 const u16* __restrict__ BT,
                                                 void* __restrict__ C, int M, int N, int K) {
  __shared__ __align__(16) u16 As[128 * 32];
  __shared__ __align__(16) u16 Bs[128 * 32];
  const int tid = threadIdx.x, wave = tid >> 6, lane = tid & 63;
  const int fr = lane & 15, fq = lane >> 4;
  const int rowBase = blockIdx.y * 128, colBase = blockIdx.x * 128;
  const int wr = wave >> 1, wc = wave & 1;
  f32x4 acc[4][4] = {};
  const int nk = K >> 5;
  for (int kt = 0; kt < nk; ++kt) {
    const int k0 = kt << 5;
#pragma unroll
    for (int p = 0; p < 2; ++p) {
      int cbase = p * 256 + wave * 64;
      int chunk = cbase + lane;
      int r = chunk >> 2, cb = chunk & 3;
      gload16(A + (size_t)(rowBase + r) * K + k0 + cb * 8, (char*)As + cbase * 16);
      gload16(BT + (size_t)(colBase + r) * K + k0 + cb * 8, (char*)Bs + cbase * 16);
    }
    __syncthreads();
    bf16x8 a[4], b[4];
#pragma unroll
    for (int m = 0; m < 4; ++m)
      a[m] = *reinterpret_cast<const bf16x8*>(&As[(wr * 64 + m * 16 + fr) * 32 + fq * 8]);
#pragma unroll
    for (int n = 0; n < 4; ++n)
      b[n] = *reinterpret_cast<const bf16x8*>(&Bs[(wc * 64 + n * 16 + fr) * 32 + fq * 8]);
#pragma unroll
    for (int m = 0; m < 4; ++m)
#pragma unroll
      for (int n = 0; n < 4; ++n)
        acc[m][n] = __builtin_amdgcn_mfma_f32_16x16x32_bf16(a[m], b[n], acc[m][n], 0, 0, 0);
    __syncthreads();
  }
#pragma unroll
  for (int m = 0; m < 4; ++m) {
    int row0 = rowBase + wr * 64 + m * 16 + fq * 4;
#pragma unroll
    for (int n = 0; n < 4; ++n) {
      int col = colBase + wc * 64 + n * 16 + fr;
#pragma unroll
      for (int j = 0; j < 4; ++j) {
        if (OUT_BF16)
          ((u16*)C)[(size_t)(row0 + j) * N + col] = f2bf(acc[m][n][j]);
        else
          ((float*)C)[(size_t)(row0 + j) * N + col] = acc[m][n][j];
      }
    }
  }
}

// ---------------- flash attention (causal, GQA) ----------------
// R8-proven kernel (139us, passed). 8 waves, 512 thr. Group A (waves 0-3) =
// k-cols 0..63 of each KT=128 step, group B (4-7) = k-cols 64..127; both cover
// the same 128 q-rows (4 pairs x 32q, swapped 32x32 MFMA + in-register softmax
// per wave). Independent online softmax per group; ONE flash-combine per
// q-tile through LDS. Serial q-tile pair {31-p, p}: every block exactly 33
// steps -> 256 blocks = 1/CU. Rule #20: all o[] indices static per-grp branch.
// (R9/R10's 16-wave variant core-dumped; reverted.)
// Qb [H][S][HD] (pre-scaled by 1/sqrt(HD)*LOG2E), Kb [KV][S][HD],
// VT [KV][HD][S], AO [S][H*HD]
__device__ __forceinline__ void stage_kv128(const u16* __restrict__ Kbk,
                                            const u16* __restrict__ VTk, int kb,
                                            char* KsB, char* VsB, int tid) {
#pragma unroll
  for (int it = 0; it < 4; ++it) {
    int slot = it * 512 + tid;
    int r = slot >> 4, cb = slot & 15;
    int cbs = cb ^ (r & 15);  // pre-swizzled source -> linear LDS dest (G21)
    gload16(Kbk + (size_t)(kb + r) * HD + cbs * 8, KsB + slot * 16);
    gload16(VTk + (size_t)r * S_LEN + kb + cbs * 8, VsB + slot * 16);
  }
}

__global__ __launch_bounds__(512, 2) void k_attn(const u16* __restrict__ Qb,
                                                 const u16* __restrict__ Kb,
                                                 const u16* __restrict__ VT,
                                                 u16* __restrict__ AO) {
  __shared__ __align__(16) u16 Ks[2][128 * 128];  // [k][d], ^(k&15) chunk swz, 64KB
  __shared__ __align__(16) u16 Vs[2][128 * 128];  // [d][k], ^(d&15) chunk swz, 64KB
  const int h = blockIdx.x;
  const int p = blockIdx.y;  // 0..15
  const int kv = h >> 2;
  const int tid = threadIdx.x, wave = tid >> 6, lane = tid & 63;
  const int grp = wave >> 2, pr = wave & 3;  // k-group, q-pair
  const int ql = lane & 31, hi = lane >> 5;
  const float DEFER_THR = 11.541560327111707f;  // 8 * log2(e)

  const u16* Kbk = Kb + (size_t)kv * S_LEN * HD;
  const u16* VTk = VT + (size_t)kv * HD * S_LEN;

#pragma unroll 1
  for (int half = 0; half < 2; ++half) {
    const int qt = half ? p : (31 - p);
    const int qg0w = qt * 128 + pr * 32;  // wave's first q row
    const int qglob = qg0w + ql;          // this lane's q row

    __syncthreads();  // prior combine readers done before restaging Ks/Vs
    stage_kv128(Kbk, VTk, 0, (char*)Ks[0], (char*)Vs[0], tid);

    // Q as B-operand frags: lane(ql,hi) holds Q[qglob][t*16 + hi*8 + e]
    bf16x8 qf[8];
    {
      const u16* qp = Qb + ((size_t)h * S_LEN + qglob) * HD;
#pragma unroll
      for (int t = 0; t < 8; ++t)
        qf[t] = *reinterpret_cast<const bf16x8*>(qp + t * 16 + hi * 8);
    }
    f32x16 o[4] = {};  // O^T: lane(q=ql,hi) holds O[q][d0*32+(r&3)+8*(r>>2)+4*hi]
    float m = -INFINITY, l = 0.f;

    __syncthreads();  // tile 0 staged

    int buf = 0;
    const int nkt = qt + 1;
    for (int kt = 0; kt < nkt; ++kt) {
      if (kt + 1 < nkt)
        stage_kv128(Kbk, VTk, (kt + 1) * 128, (char*)Ks[buf ^ 1], (char*)Vs[buf ^ 1], tid);
      const int kbg = kt * 128 + grp * 64;  // this group's k base
      if (kbg <= qg0w + 31) {               // wave has >=1 unmasked column
        const char* Kc = (const char*)Ks[buf];
        const char* Vc = (const char*)Vs[buf];

        // S^T = mfma(A=K rows, B=Q): st0 = group k 0..31, st1 = 32..63
        f32x16 st0 = {}, st1 = {};
#pragma unroll
        for (int t = 0; t < 8; ++t) {
          int ch = (2 * t + hi) ^ (ql & 15);
          const int r0 = grp * 64 + ql, r1 = grp * 64 + 32 + ql;
          bf16x8 kf0 = *reinterpret_cast<const bf16x8*>(Kc + r0 * 256 + ch * 16);
          bf16x8 kf1 = *reinterpret_cast<const bf16x8*>(Kc + r1 * 256 + ch * 16);
          st0 = __builtin_amdgcn_mfma_f32_32x32x16_bf16(kf0, qf[t], st0, 0, 0, 0);
          st1 = __builtin_amdgcn_mfma_f32_32x32x16_bf16(kf1, qf[t], st1, 0, 0, 0);
        }
        // causal mask: lane reg r holds k_local = (r&3)+8*(r>>2)+4*hi
        if (kbg + 63 > qg0w) {
#pragma unroll
          for (int r = 0; r < 16; ++r) {
            int kl = (r & 3) + 8 * (r >> 2) + 4 * hi;
            if (kbg + kl > qglob) st0[r] = -1e30f;
            if (kbg + 32 + kl > qglob) st1[r] = -1e30f;
          }
        }
        // row max: in-lane tree over 32 values, then lane-pair combine (xor 32)
        float mx[16];
#pragma unroll
        for (int r = 0; r < 16; ++r) mx[r] = fmaxf(st0[r], st1[r]);
#pragma unroll
        for (int s = 8; s > 0; s >>= 1)
#pragma unroll
          for (int r = 0; r < 16; ++r)
            if (r < s) mx[r] = fmaxf(mx[r], mx[r + s]);
        float tmax = fmaxf(mx[0], __shfl_xor(mx[0], 32));
        // defer-max (T13)
        if (__any(tmax - m > DEFER_THR)) {
          float mn = fmaxf(m, tmax);
          float corr = exp2f(m - mn);
          m = mn;
          l *= corr;
#pragma unroll
          for (int d0 = 0; d0 < 4; ++d0) o[d0] *= corr;
        }
        // P = exp2(S - m); in-lane sum + lane-pair combine
        float sm[16];
#pragma unroll
        for (int r = 0; r < 16; ++r) {
          st0[r] = exp2f(st0[r] - m);
          st1[r] = exp2f(st1[r] - m);
          sm[r] = st0[r] + st1[r];
        }
#pragma unroll
        for (int s = 8; s > 0; s >>= 1)
#pragma unroll
          for (int r = 0; r < 16; ++r)
            if (r < s) sm[r] += sm[r + s];
        l += sm[0] + __shfl_xor(sm[0], 32);

        // P -> bf16 B-frags in-register (pack + shfl_xor(32) + select).
        // Frag slot (hi,e) holds P[q][kc*16 + hi*8 + e] (k local to group).
        bf16x8 pa[4];
#pragma unroll
        for (int kc = 0; kc < 4; ++kc) {
          int rb = 8 * (kc & 1);
          u32 w0, w1, w2, w3;
          if (kc < 2) {
            w0 = pk2(st0[rb + 0], st0[rb + 1]);
            w1 = pk2(st0[rb + 2], st0[rb + 3]);
            w2 = pk2(st0[rb + 4], st0[rb + 5]);
            w3 = pk2(st0[rb + 6], st0[rb + 7]);
          } else {
            w0 = pk2(st1[rb + 0], st1[rb + 1]);
            w1 = pk2(st1[rb + 2], st1[rb + 3]);
            w2 = pk2(st1[rb + 4], st1[rb + 5]);
            w3 = pk2(st1[rb + 6], st1[rb + 7]);
          }
          u32 xw0 = (u32)__shfl_xor((int)w0, 32);
          u32 xw1 = (u32)__shfl_xor((int)w1, 32);
          u32 xw2 = (u32)__shfl_xor((int)w2, 32);
          u32 xw3 = (u32)__shfl_xor((int)w3, 32);
          i32x4 pw;
          pw[0] = (int)(hi ? xw2 : w0);
          pw[1] = (int)(hi ? xw3 : w1);
          pw[2] = (int)(hi ? w2 : xw0);
          pw[3] = (int)(hi ? w3 : xw1);
          pa[kc] = __builtin_bit_cast(bf16x8, pw);
        }
        // O^T += mfma(A=V^T rows, B=P^T) over this group's 64 k-cols
#pragma unroll
        for (int d0 = 0; d0 < 4; ++d0) {
          int dr = d0 * 32 + ql;
#pragma unroll
          for (int kc = 0; kc < 4; ++kc) {
            int ch = (grp * 8 + 2 * kc + hi) ^ (ql & 15);
            bf16x8 vf = *reinterpret_cast<const bf16x8*>(Vc + dr * 256 + ch * 16);
            o[d0] = __builtin_amdgcn_mfma_f32_32x32x16_bf16(vf, pa[kc], o[d0], 0, 0, 0);
          }
        }
      }
      __syncthreads();  // next tile staged; buf safe to flip
      buf ^= 1;
    }

    // ---- flash-combine of the two k-groups (once per q-tile) ----
    // grp 0: stores o[2],o[3] for partner, merges+writes d0 0,1.
    // grp 1: stores o[0],o[1] for partner, merges+writes d0 2,3.
    // STATIC o[] indices only (rule #20) — branch on wave-uniform grp.
    float2* exch = (float2*)Ks;  // [d0 4][rp 8][pr 4][lane 64] float2 = 64KB
    float2* mlb = (float2*)Vs;   // [grp 2][pr 4][ql 32] float2
    if (grp == 0) {
#pragma unroll
      for (int rp = 0; rp < 8; ++rp) {
        float2 v2, v3;
        v2.x = o[2][2 * rp]; v2.y = o[2][2 * rp + 1];
        v3.x = o[3][2 * rp]; v3.y = o[3][2 * rp + 1];
        exch[((2 * 8 + rp) * 4 + pr) * 64 + lane] = v2;
        exch[((3 * 8 + rp) * 4 + pr) * 64 + lane] = v3;
      }
    } else {
#pragma unroll
      for (int rp = 0; rp < 8; ++rp) {
        float2 v0, v1;
        v0.x = o[0][2 * rp]; v0.y = o[0][2 * rp + 1];
        v1.x = o[1][2 * rp]; v1.y = o[1][2 * rp + 1];
        exch[((0 * 8 + rp) * 4 + pr) * 64 + lane] = v0;
        exch[((1 * 8 + rp) * 4 + pr) * 64 + lane] = v1;
      }
    }
    if (hi == 0) {
      float2 v;
      v.x = m;
      v.y = l;
      mlb[(grp * 4 + pr) * 32 + ql] = v;
    }
    __syncthreads();
    {
      float2 pml = mlb[((1 - grp) * 4 + pr) * 32 + ql];
      float mm = fmaxf(m, pml.x);
      float fa = exp2f(m - mm), fb = exp2f(pml.x - mm);
      float ll = l * fa + pml.y * fb;
      float inv = 1.0f / ll;
      u16* aoRow = AO + (size_t)qglob * DMODEL + h * HD;
      if (grp == 0) {
#pragma unroll
        for (int rp = 0; rp < 8; ++rp) {
          int r = 2 * rp;
          int dbase = (r & 3) + 8 * (r >> 2) + 4 * hi;
          float2 po0 = exch[((0 * 8 + rp) * 4 + pr) * 64 + lane];
          float u0 = (o[0][r] * fa + po0.x * fb) * inv;
          float u1 = (o[0][r + 1] * fa + po0.y * fb) * inv;
          *reinterpret_cast<u32*>(aoRow + 0 * 32 + dbase) = pk2(u0, u1);
          float2 po1 = exch[((1 * 8 + rp) * 4 + pr) * 64 + lane];
          u0 = (o[1][r] * fa + po1.x * fb) * inv;
          u1 = (o[1][r + 1] * fa + po1.y * fb) * inv;
          *reinterpret_cast<u32*>(aoRow + 1 * 32 + dbase) = pk2(u0, u1);
        }
      } else {
#pragma unroll
        for (int rp = 0; rp < 8; ++rp) {
          int r = 2 * rp;
          int dbase = (r & 3) + 8 * (r >> 2) + 4 * hi;
          float2 po2 = exch[((2 * 8 + rp) * 4 + pr) * 64 + lane];
          float u0 = (o[2][r] * fa + po2.x * fb) * inv;
          float u1 = (o[2][r + 1] * fa + po2.y * fb) * inv;
          *reinterpret_cast<u32*>(aoRow + 2 * 32 + dbase) = pk2(u0, u1);
          float2 po3 = exch[((3 * 8 + rp) * 4 + pr) * 64 + lane];
          u0 = (o[3][r] * fa + po3.x * fb) * inv;
          u1 = (o[3][r + 1] * fa + po3.y * fb) * inv;
          *reinterpret_cast<u32*>(aoRow + 3 * 32 + dbase) = pk2(u0, u1);
        }
      }
    }
    // loop-top __syncthreads protects Ks/Vs before next tile's staging
  }
}

// ---------------- launch ----------------
extern "C" void kernel_launch(void* const* d_in, const int* in_sizes, int n_in,
                              void* d_out, int out_size, void* d_ws, size_t ws_size,
                              hipStream_t stream) {
  const float* hidden = (const float*)d_in[0];
  const float* Wq = (const float*)d_in[1];
  const float* Wk = (const float*)d_in[2];
  const float* Wv = (const float*)d_in[3];
  const float* Wo = (const float*)d_in[4];
  // d_in[5] = attention_mask: causal, applied analytically (unused)
  const int* pos_ids = (const int*)d_in[6];
  float* out = (float*)d_out;

  char* ws = (char*)d_ws;
  u16* Xb   = (u16*)(ws);                               // [4096][2048]   16MB
  u16* Wt   = (u16*)(ws + (16ull << 20));               // [3072][2048]   12MB
  u16* WoT  = (u16*)(ws + (28ull << 20));               // [2048][2048]    8MB
  u16* QKVb = (u16*)(ws + (36ull << 20));               // [4096][3072]   24MB
  u16* Qb   = (u16*)(ws + (60ull << 20));               // [16][4096][128] 16MB
  u16* Kb   = (u16*)(ws + (76ull << 20));               // [4][4096][128]   4MB
  u16* VT   = (u16*)(ws + (80ull << 20));               // [4][128][4096]   4MB
  // tab overlaps VT's 2nd half (82..84MB). Lifetime per replay: rope_tab
  // writes tab -> gemm -> rope READS tab -> transpose writes VT (clobbers
  // dead tab) -> attn reads VT. Single stream => deterministic.
  float2* tab = (float2*)(ws + (82ull << 20));          // [4096][64]       2MB
  u16* AO   = QKVb;  // alias: QKVb fully consumed before attention writes AO

  dim3 tb(32, 8);
  k_f32_to_bf16<<<dim3((S_LEN * DMODEL / 4) / 256), dim3(256), 0, stream>>>(
      hidden, Xb, S_LEN * DMODEL / 4);
  k_transpose_f32_bf16<<<dim3(64, 64), tb, 0, stream>>>(Wq, 2048, Wt, 2048);
  k_transpose_f32_bf16<<<dim3(16, 64), tb, 0, stream>>>(Wk, 512, Wt + (size_t)2048 * 2048, 2048);
  k_transpose_f32_bf16<<<dim3(16, 64), tb, 0, stream>>>(Wv, 512, Wt + (size_t)2560 * 2048, 2048);
  k_transpose_f32_bf16<<<dim3(64, 64), tb, 0, stream>>>(Wo, 2048, WoT, 2048);
  k_rope_tab<<<dim3(S_LEN * 64 / 256), dim3(256), 0, stream>>>(pos_ids, tab);

  k_gemm_bt<1><<<dim3(24, 32), 256, 0, stream>>>(Xb, Wt, QKVb, S_LEN, NQKV, DMODEL);

  k_rope<<<dim3(S_LEN), 256, 0, stream>>>(QKVb, tab, Qb, Kb);
  k_transpose_bf16<<<dim3(16, 128), tb, 0, stream>>>(QKVb + 2560, NQKV, VT, S_LEN);

  k_attn<<<dim3(NH, 16), 512, 0, stream>>>(Qb, Kb, VT, AO);

  k_gemm_bt<0><<<dim3(16, 32), 256, 0, stream>>>(AO, WoT, out, S_LEN, DMODEL, DMODEL);
}